// Round 2
// baseline (345.971 us; speedup 1.0000x reference)
//
#include <hip/hip_runtime.h>
#include <math.h>

// CorrespondenceContrastiveLoss on MI355X.
// feat [1,64,100,88,80] f32; points [16384,3] i32 (3 sets).
// One wave (64 lanes) per point: lane = channel. Scattered gathers dominate.

#define WAVES_PER_BLOCK 4
#define BLOCK_SIZE 256

#define CX 100
#define CY 88
#define CZ 80
#define VOXELS (CX * CY * CZ)   // 704000 = per-channel stride

__device__ __forceinline__ int redirect(int v, int idx, int m) {
    int t = (v - idx) % m;      // compiler emits magic-multiply
    return t < 0 ? t + m : t;
}

__global__ __launch_bounds__(BLOCK_SIZE)
void ccl_partial_kernel(const float* __restrict__ fix,
                        const float* __restrict__ mov,
                        const int* __restrict__ fpts,
                        const int* __restrict__ ppts,
                        const int* __restrict__ npts,
                        double* __restrict__ partial,
                        int B)
{
    const int wave = threadIdx.x >> 6;
    const int lane = threadIdx.x & 63;
    const int b = blockIdx.x * WAVES_PER_BLOCK + wave;

    float contrib = 0.0f;
    if (b < B) {
        const int fx = redirect(fpts[b * 3 + 0], 25, CX);
        const int fy = redirect(fpts[b * 3 + 1], 225, CY);
        const int fz = redirect(fpts[b * 3 + 2], 28, CZ);
        const int px = redirect(ppts[b * 3 + 0], 25, CX);
        const int py = redirect(ppts[b * 3 + 1], 225, CY);
        const int pz = redirect(ppts[b * 3 + 2], 28, CZ);
        const int nx = redirect(npts[b * 3 + 0], 25, CX);
        const int ny = redirect(npts[b * 3 + 1], 225, CY);
        const int nz = redirect(npts[b * 3 + 2], 28, CZ);

        const long fo = ((long)fx * CY + fy) * CZ + fz;
        const long po = ((long)px * CY + py) * CZ + pz;
        const long no = ((long)nx * CY + ny) * CZ + nz;
        const long coff = (long)lane * VOXELS;   // lane = channel

        const float vf = fix[coff + fo];
        const float vp = mov[coff + po];
        const float vn = mov[coff + no];

        float dp = vf - vp; dp *= dp;
        float dn = vf - vn; dn *= dn;

        #pragma unroll
        for (int m = 32; m >= 1; m >>= 1) {
            dp += __shfl_xor(dp, m, 64);
            dn += __shfl_xor(dn, m, 64);
        }

        if (lane == 0) {
            const float lp = dp * dp;                        // d_pos^2
            const float t = fmaxf(0.0f, 1.0f - sqrtf(dn));   // hinge
            contrib = lp + t * t;
        }
    }

    // Block reduce: 4 wave-leader floats -> one double partial
    __shared__ float s[WAVES_PER_BLOCK];
    if (lane == 0) s[wave] = contrib;
    __syncthreads();
    if (threadIdx.x == 0) {
        double sum = 0.0;
        #pragma unroll
        for (int w = 0; w < WAVES_PER_BLOCK; ++w) sum += (double)s[w];
        partial[blockIdx.x] = sum;
    }
}

__global__ __launch_bounds__(256)
void ccl_final_kernel(const double* __restrict__ partial, int n,
                      float* __restrict__ out, double scale)
{
    __shared__ double s[256];
    double sum = 0.0;
    for (int i = threadIdx.x; i < n; i += 256) sum += partial[i];
    s[threadIdx.x] = sum;
    __syncthreads();
    #pragma unroll
    for (int st = 128; st >= 1; st >>= 1) {
        if (threadIdx.x < st) s[threadIdx.x] += s[threadIdx.x + st];
        __syncthreads();
    }
    if (threadIdx.x == 0) out[0] = (float)(s[0] * scale);
}

extern "C" void kernel_launch(void* const* d_in, const int* in_sizes, int n_in,
                              void* d_out, int out_size, void* d_ws, size_t ws_size,
                              hipStream_t stream)
{
    const float* fix = (const float*)d_in[0];
    const float* mov = (const float*)d_in[1];
    const int* fpts = (const int*)d_in[2];
    const int* ppts = (const int*)d_in[3];
    const int* npts = (const int*)d_in[4];
    float* out = (float*)d_out;

    const int B = in_sizes[2] / 3;                 // 16384
    const int nblocks = (B + WAVES_PER_BLOCK - 1) / WAVES_PER_BLOCK;

    double* partial = (double*)d_ws;               // nblocks * 8 B, fits ws

    ccl_partial_kernel<<<nblocks, BLOCK_SIZE, 0, stream>>>(
        fix, mov, fpts, ppts, npts, partial, B);

    const double scale = 1.0e6 / (4.0 * (double)B);   // /(2*2B) * 1e6
    ccl_final_kernel<<<1, 256, 0, stream>>>(partial, nblocks, out, scale);
}

// Round 3
// 345.948 us; speedup vs baseline: 1.0001x; 1.0001x over previous
//
#include <hip/hip_runtime.h>
#include <math.h>

// CorrespondenceContrastiveLoss on MI355X.
// feat [1,64,100,88,80] f32; points [16384,3] i32 (3 sets).
// One wave (64 lanes) handles TWO points (lane = channel); 6 independent
// scattered line-loads in flight per wave to cover HBM latency*BW.

#define WAVES_PER_BLOCK 4
#define PTS_PER_WAVE 2
#define BLOCK_SIZE 256

#define CX 100
#define CY 88
#define CZ 80
#define VOXELS (CX * CY * CZ)   // 704000 = per-channel stride

__device__ __forceinline__ int redirect(int v, int idx, int m) {
    int t = (v - idx) % m;      // magic-multiply, no div unit
    return t < 0 ? t + m : t;
}

__device__ __forceinline__ long voxoff(const int* __restrict__ p, int b) {
    const int x = redirect(p[b * 3 + 0], 25, CX);
    const int y = redirect(p[b * 3 + 1], 225, CY);
    const int z = redirect(p[b * 3 + 2], 28, CZ);
    return ((long)x * CY + y) * CZ + z;
}

__global__ __launch_bounds__(BLOCK_SIZE)
void ccl_partial_kernel(const float* __restrict__ fix,
                        const float* __restrict__ mov,
                        const int* __restrict__ fpts,
                        const int* __restrict__ ppts,
                        const int* __restrict__ npts,
                        double* __restrict__ partial,
                        int B)
{
    const int wave = threadIdx.x >> 6;
    const int lane = threadIdx.x & 63;
    const int w = blockIdx.x * WAVES_PER_BLOCK + wave;
    const int b0 = w * PTS_PER_WAVE;

    const long coff = (long)lane * VOXELS;   // lane = channel

    float contrib = 0.0f;
    if (b0 + 1 < B) {
        // All 6 offsets first, then 6 independent gather loads in flight.
        const long fo0 = voxoff(fpts, b0),     fo1 = voxoff(fpts, b0 + 1);
        const long po0 = voxoff(ppts, b0),     po1 = voxoff(ppts, b0 + 1);
        const long no0 = voxoff(npts, b0),     no1 = voxoff(npts, b0 + 1);

        const float vf0 = fix[coff + fo0];
        const float vf1 = fix[coff + fo1];
        const float vp0 = mov[coff + po0];
        const float vp1 = mov[coff + po1];
        const float vn0 = mov[coff + no0];
        const float vn1 = mov[coff + no1];

        float dp0 = vf0 - vp0; dp0 *= dp0;
        float dn0 = vf0 - vn0; dn0 *= dn0;
        float dp1 = vf1 - vp1; dp1 *= dp1;
        float dn1 = vf1 - vn1; dn1 *= dn1;

        #pragma unroll
        for (int m = 32; m >= 1; m >>= 1) {
            dp0 += __shfl_xor(dp0, m, 64);
            dn0 += __shfl_xor(dn0, m, 64);
            dp1 += __shfl_xor(dp1, m, 64);
            dn1 += __shfl_xor(dn1, m, 64);
        }

        if (lane == 0) {
            const float t0 = fmaxf(0.0f, 1.0f - sqrtf(dn0));
            const float t1 = fmaxf(0.0f, 1.0f - sqrtf(dn1));
            contrib = dp0 * dp0 + t0 * t0 + dp1 * dp1 + t1 * t1;
        }
    } else {
        // tail: per-point scalar path (B=16384 is even, but stay correct)
        for (int b = b0; b < B; ++b) {
            const long fo = voxoff(fpts, b);
            const long po = voxoff(ppts, b);
            const long no = voxoff(npts, b);
            const float vf = fix[coff + fo];
            const float vp = mov[coff + po];
            const float vn = mov[coff + no];
            float dp = vf - vp; dp *= dp;
            float dn = vf - vn; dn *= dn;
            #pragma unroll
            for (int m = 32; m >= 1; m >>= 1) {
                dp += __shfl_xor(dp, m, 64);
                dn += __shfl_xor(dn, m, 64);
            }
            if (lane == 0) {
                const float t = fmaxf(0.0f, 1.0f - sqrtf(dn));
                contrib += dp * dp + t * t;
            }
        }
    }

    __shared__ float s[WAVES_PER_BLOCK];
    if (lane == 0) s[wave] = contrib;
    __syncthreads();
    if (threadIdx.x == 0) {
        double sum = 0.0;
        #pragma unroll
        for (int v = 0; v < WAVES_PER_BLOCK; ++v) sum += (double)s[v];
        partial[blockIdx.x] = sum;
    }
}

__global__ __launch_bounds__(256)
void ccl_final_kernel(const double* __restrict__ partial, int n,
                      float* __restrict__ out, double scale)
{
    __shared__ double s[256];
    double sum = 0.0;
    for (int i = threadIdx.x; i < n; i += 256) sum += partial[i];
    s[threadIdx.x] = sum;
    __syncthreads();
    #pragma unroll
    for (int st = 128; st >= 1; st >>= 1) {
        if (threadIdx.x < st) s[threadIdx.x] += s[threadIdx.x + st];
        __syncthreads();
    }
    if (threadIdx.x == 0) out[0] = (float)(s[0] * scale);
}

extern "C" void kernel_launch(void* const* d_in, const int* in_sizes, int n_in,
                              void* d_out, int out_size, void* d_ws, size_t ws_size,
                              hipStream_t stream)
{
    const float* fix = (const float*)d_in[0];
    const float* mov = (const float*)d_in[1];
    const int* fpts = (const int*)d_in[2];
    const int* ppts = (const int*)d_in[3];
    const int* npts = (const int*)d_in[4];
    float* out = (float*)d_out;

    const int B = in_sizes[2] / 3;                 // 16384
    const int pts_per_block = WAVES_PER_BLOCK * PTS_PER_WAVE;
    const int nblocks = (B + pts_per_block - 1) / pts_per_block;   // 2048

    double* partial = (double*)d_ws;               // nblocks * 8 B

    ccl_partial_kernel<<<nblocks, BLOCK_SIZE, 0, stream>>>(
        fix, mov, fpts, ppts, npts, partial, B);

    const double scale = 1.0e6 / (4.0 * (double)B);   // /(2*2B) * 1e6
    ccl_final_kernel<<<1, 256, 0, stream>>>(partial, nblocks, out, scale);
}